// Round 7
// baseline (1075.223 us; speedup 1.0000x reference)
//
#include <hip/hip_runtime.h>
#include <cstdint>
#include <cstddef>

// Problem dims (fixed by reference)
#define NT_   8192
#define DIN_  2048
#define H_    2048
#define C_    16
#define G_    2
#define D_    256
#define WA_   35
#define DECH_ 512
#define NPAD_ 1280   // 1120 padded to 5*256

typedef _Float16 f16;
typedef _Float16 h4 __attribute__((ext_vector_type(4)));
typedef _Float16 h8 __attribute__((ext_vector_type(8)));
typedef float fx4 __attribute__((ext_vector_type(4)));
typedef float fx16 __attribute__((ext_vector_type(16)));

typedef __attribute__((address_space(1))) const void gvoid_t;
typedef __attribute__((address_space(3))) void lvoid_t;

// async global->LDS, 16B per lane; LDS dest = wave-uniform base + lane*16
__device__ __forceinline__ void gld16(const void* g, void* l) {
  __builtin_amdgcn_global_load_lds((gvoid_t*)(uintptr_t)g,
                                   (lvoid_t*)(uint32_t)(uintptr_t)l, 16, 0, 0);
}

__device__ __forceinline__ void barrier_() {
  asm volatile("" ::: "memory");
  __builtin_amdgcn_s_barrier();
  asm volatile("" ::: "memory");
}

template <int N>
__device__ __forceinline__ void waitvm() {
  if constexpr (N == 8)      asm volatile("s_waitcnt vmcnt(8)" ::: "memory");
  else if constexpr (N == 6) asm volatile("s_waitcnt vmcnt(6)" ::: "memory");
  else if constexpr (N == 5) asm volatile("s_waitcnt vmcnt(5)" ::: "memory");
  else if constexpr (N == 4) asm volatile("s_waitcnt vmcnt(4)" ::: "memory");
  else if constexpr (N == 2) asm volatile("s_waitcnt vmcnt(2)" ::: "memory");
  else                       asm volatile("s_waitcnt vmcnt(0)" ::: "memory");
}

#define MFMA_(d, a, b)  d = __builtin_amdgcn_mfma_f32_16x16x32_f16(a, b, d, 0, 0, 0)
#define MFMA32_(d, a, b) d = __builtin_amdgcn_mfma_f32_32x32x16_f16(a, b, d, 0, 0, 0)

// ---------------- threefry2x32 (Random123 / JAX-compatible) ----------------
__host__ __device__ inline void tf2x32(uint32_t k0, uint32_t k1,
                                       uint32_t x0, uint32_t x1,
                                       uint32_t& o0, uint32_t& o1) {
  const uint32_t ks2 = k0 ^ k1 ^ 0x1BD11BDAu;
  uint32_t ks[3] = {k0, k1, ks2};
  x0 += ks[0]; x1 += ks[1];
  const uint32_t R0[4] = {13u, 15u, 26u, 6u};
  const uint32_t R1[4] = {17u, 29u, 16u, 24u};
#pragma unroll
  for (int g = 0; g < 5; ++g) {
    const uint32_t* R = (g & 1) ? R1 : R0;
#pragma unroll
    for (int r = 0; r < 4; ++r) {
      x0 += x1;
      x1 = (x1 << R[r]) | (x1 >> (32u - R[r]));
      x1 ^= x0;
    }
    x0 += ks[(g + 1) % 3];
    x1 += ks[(g + 2) % 3] + (uint32_t)(g + 1);
  }
  o0 = x0; o1 = x1;
}

// ---------------- x split: fp32 -> f16 hi/lo --------------------------------
__global__ __launch_bounds__(256) void xsplit_kernel(
    const float* __restrict__ x, f16* __restrict__ xh, f16* __restrict__ xl) {
  const size_t i = (size_t)blockIdx.x * 256 + threadIdx.x;  // per 8 floats
  const float4 v0 = *(const float4*)(x + i * 8);
  const float4 v1 = *(const float4*)(x + i * 8 + 4);
  float vv[8] = {v0.x, v0.y, v0.z, v0.w, v1.x, v1.y, v1.z, v1.w};
  h8 hh, ll;
#pragma unroll
  for (int k = 0; k < 8; ++k) {
    const f16 h = (f16)vv[k];
    hh[k] = h;
    ll[k] = (f16)(vv[k] - (float)h);
  }
  *(h8*)(xh + i * 8) = hh;
  *(h8*)(xl + i * 8) = ll;
}

// ============ 256x256 3-term 16x16x32 GEMM w/ LOGIT epilogue ================
// (proven round-5 structure; used for w12, w21)
enum { EPI_PAIR = 0, EPI_HI = 1, EPI_LOGIT = 2 };

template <int GATHER, int EPI>
__global__ __launch_bounds__(512, 2) void gemm256(
    const f16* __restrict__ Ah, const f16* __restrict__ Al,
    const f16* __restrict__ Bh, const f16* __restrict__ Bl,
    const float* __restrict__ bias,
    f16* __restrict__ Chi, f16* __restrict__ Clo,
    int M, int N, int K,
    const int* __restrict__ gidx, const float* __restrict__ growp, int gldw,
    const float* __restrict__ wlog, float* __restrict__ part) {
  extern __shared__ f16 lds[];
  constexpr int BS = 4 * 8192;

  const int tid  = threadIdx.x;
  const int wave = tid >> 6;
  const int lane = tid & 63;
  const int lr   = lane & 15;

  const int nb  = N >> 8;
  const int nwg = (int)gridDim.x;
  const int qq  = nwg >> 3;
  const int sw  = ((int)blockIdx.x & 7) * qq + ((int)blockIdx.x >> 3);
  const int by  = sw / nb, bx = sw % nb;
  const int m0  = by << 8, n0 = bx << 8;

  const int wm = (wave >> 2) * 128;
  const int wn = (wave & 3) * 64;

  fx4 acc[8][4];
#pragma unroll
  for (int i = 0; i < 8; ++i)
#pragma unroll
    for (int j = 0; j < 4; ++j) acc[i][j] = (fx4){0.f, 0.f, 0.f, 0.f};

  const int r_row = wave * 16 + (lane >> 2);
  const int r_g   = (lane & 3) ^ ((lane >> 3) & 3);
  // issue order: 0:Bh0 1:Bh1 2:Bl0 3:Bl1 4:Ah0 5:Ah1 6:Al0 7:Al1
  const f16* gsrc[8];
  int gdst[8];
  {
    int nr = 0;
    auto AR = [&](const f16* P, int mn, int reg, int rb) {
      gsrc[nr] = P + (size_t)(mn + rb + r_row) * K + r_g * 8;
      gdst[nr] = reg * 8192 + rb * 32 + wave * 512;
      ++nr;
    };
    AR(Bh, n0, 2, 0); AR(Bh, n0, 2, 128);
    AR(Bl, n0, 3, 0); AR(Bl, n0, 3, 128);
    AR(Ah, m0, 0, 0); AR(Ah, m0, 0, 128);
    AR(Al, m0, 1, 0); AR(Al, m0, 1, 128);
  }

#pragma unroll
  for (int r = 0; r < 8; ++r) gld16(gsrc[r], lds + gdst[r]);
  waitvm<2>();
  barrier_();

  const int pg8 = ((lane >> 4) ^ ((lr >> 1) & 3)) * 8;
  const int KT  = K >> 5;

  for (int t = 0; t < KT; ++t) {
    f16* const sb  = lds + (t & 1) * BS;
    f16* const nsb = lds + ((t + 1) & 1) * BS;
    const int ktn = (t + 1 < KT ? t + 1 : t) * 32;

    const f16* sAh = sb;
    const f16* sAl = sb + 8192;
    const f16* sBh = sb + 16384;
    const f16* sBl = sb + 24576;

    h8 vbh[4], vbl[4], va[4];
#pragma unroll
    for (int j = 0; j < 4; ++j) {
      vbh[j] = *(const h8*)(sBh + (wn + j * 16 + lr) * 32 + pg8);
      vbl[j] = *(const h8*)(sBl + (wn + j * 16 + lr) * 32 + pg8);
    }
#pragma unroll
    for (int i = 0; i < 4; ++i)
      va[i] = *(const h8*)(sAh + (wm + i * 16 + lr) * 32 + pg8);
    gld16(gsrc[0] + ktn, nsb + gdst[0]);
    gld16(gsrc[1] + ktn, nsb + gdst[1]);
    gld16(gsrc[2] + ktn, nsb + gdst[2]);
    barrier_();
    asm volatile("s_waitcnt lgkmcnt(0)" ::: "memory");
    __builtin_amdgcn_sched_barrier(0);
    __builtin_amdgcn_s_setprio(1);
#pragma unroll
    for (int i = 0; i < 4; ++i)
#pragma unroll
      for (int j = 0; j < 4; ++j) MFMA_(acc[i][j], va[i], vbh[j]);
#pragma unroll
    for (int i = 0; i < 4; ++i)
#pragma unroll
      for (int j = 0; j < 4; ++j) MFMA_(acc[i][j], va[i], vbl[j]);
    __builtin_amdgcn_s_setprio(0);
    barrier_();
#pragma unroll
    for (int i = 0; i < 4; ++i)
      va[i] = *(const h8*)(sAh + (wm + 64 + i * 16 + lr) * 32 + pg8);
    gld16(gsrc[3] + ktn, nsb + gdst[3]);
    gld16(gsrc[4] + ktn, nsb + gdst[4]);
    gld16(gsrc[5] + ktn, nsb + gdst[5]);
    barrier_();
    asm volatile("s_waitcnt lgkmcnt(0)" ::: "memory");
    __builtin_amdgcn_sched_barrier(0);
    __builtin_amdgcn_s_setprio(1);
#pragma unroll
    for (int i = 0; i < 4; ++i)
#pragma unroll
      for (int j = 0; j < 4; ++j) MFMA_(acc[4 + i][j], va[i], vbh[j]);
#pragma unroll
    for (int i = 0; i < 4; ++i)
#pragma unroll
      for (int j = 0; j < 4; ++j) MFMA_(acc[4 + i][j], va[i], vbl[j]);
    __builtin_amdgcn_s_setprio(0);
    waitvm<6>();
    barrier_();
    {
      h8 vl0[4], vl1[4];
#pragma unroll
      for (int i = 0; i < 4; ++i) {
        vl0[i] = *(const h8*)(sAl + (wm + i * 16 + lr) * 32 + pg8);
        vl1[i] = *(const h8*)(sAl + (wm + 64 + i * 16 + lr) * 32 + pg8);
      }
      gld16(gsrc[6] + ktn, nsb + gdst[6]);
      gld16(gsrc[7] + ktn, nsb + gdst[7]);
      barrier_();
      asm volatile("s_waitcnt lgkmcnt(0)" ::: "memory");
      __builtin_amdgcn_sched_barrier(0);
      __builtin_amdgcn_s_setprio(1);
#pragma unroll
      for (int i = 0; i < 4; ++i)
#pragma unroll
        for (int j = 0; j < 4; ++j) {
          MFMA_(acc[i][j], vl0[i], vbh[j]);
          MFMA_(acc[4 + i][j], vl1[i], vbh[j]);
        }
      __builtin_amdgcn_s_setprio(0);
      waitvm<2>();
      barrier_();
    }
  }

  const int rq = (lane >> 4) * 4;
  if constexpr (EPI == EPI_LOGIT) {
#pragma unroll
    for (int mi = 0; mi < 8; ++mi) {
#pragma unroll
      for (int q = 0; q < 4; ++q) {
        const int row = m0 + wm + mi * 16 + rq + q;
        const float* gr = nullptr;
        if constexpr (GATHER) gr = growp + (size_t)gidx[row] * gldw;
#pragma unroll
        for (int j = 0; j < 4; ++j) {
          const int col = n0 + wn + j * 16 + lr;
          float v = acc[mi][j][q] + bias[col];
          if constexpr (GATHER) v += gr[col];
          acc[mi][j][q] = fmaxf(v, 0.f);
        }
      }
    }
    waitvm<0>();
    barrier_();
    float* psm = (float*)lds + wave * 2560;
    const int sidx = bx * 4 + (wave & 3);
    const int q_l = ((lr & 1) << 1) | ((lr >> 1) & 1);
    const int c_l = (((lr >> 2) & 1) << 1) | ((lr >> 3) & 1);
#pragma unroll
    for (int cc = 0; cc < 4; ++cc) {
      float wc[4][4];
#pragma unroll
      for (int j = 0; j < 4; ++j) {
        const float4 wv = *(const float4*)(wlog +
            (size_t)(n0 + wn + j * 16 + lr) * 16 + cc * 4);
        wc[j][0] = wv.x; wc[j][1] = wv.y; wc[j][2] = wv.z; wc[j][3] = wv.w;
      }
#pragma unroll
      for (int mi = 0; mi < 8; ++mi) {
        float A[16];
#pragma unroll
        for (int i = 0; i < 16; ++i) {
          float s = 0.f;
#pragma unroll
          for (int j = 0; j < 4; ++j)
            s = fmaf(acc[mi][j][i >> 2], wc[j][i & 3], s);
          A[i] = s;
        }
#pragma unroll
        for (int k = 0; k < 4; ++k) {
          const int L2 = 8 >> k;
          const bool b = (lr >> k) & 1;
          float An[8];
#pragma unroll
          for (int i = 0; i < L2; ++i) {
            const float keep = b ? A[i + L2] : A[i];
            const float send = b ? A[i] : A[i + L2];
            An[i] = keep + __shfl_xor(send, 1 << k);
          }
#pragma unroll
          for (int i = 0; i < L2; ++i) A[i] = An[i];
        }
        psm[mi * 320 + (rq + q_l) * 20 + cc * 4 + c_l] = A[0];
      }
    }
    asm volatile("s_waitcnt lgkmcnt(0)" ::: "memory");
#pragma unroll
    for (int mi = 0; mi < 8; ++mi) {
      const float4 o = *(const float4*)(psm + mi * 320 +
                                        (lane >> 2) * 20 + (lane & 3) * 4);
      float* pout = part + ((size_t)sidx * NT_ +
                            (m0 + wm + mi * 16 + (lane >> 2))) * 16 +
                    (lane & 3) * 4;
      *(float4*)pout = o;
    }
  } else {
#pragma unroll
    for (int mi = 0; mi < 8; ++mi) {
#pragma unroll
      for (int q = 0; q < 4; ++q) {
        const int row = m0 + wm + mi * 16 + rq + q;
#pragma unroll
        for (int j = 0; j < 4; ++j) {
          const int col = n0 + wn + j * 16 + lr;
          float v = fmaxf(acc[mi][j][q] + bias[col], 0.f);
          const f16 hh = (f16)v;
          Chi[(size_t)row * N + col] = hh;
          if constexpr (EPI == EPI_PAIR)
            Clo[(size_t)row * N + col] = (f16)(v - (float)hh);
        }
      }
    }
  }
}

// ======= 256x256 3-term 32x32x16 GEMM, PAIR epilogue (w11) ==================
// Granule-major LDS: each 128-row x 32-f16 region half = 4 planes of
// [k-granule][row] 16B slots; gld16 source permuted to match (rule #21).
// Read slot = (2k+hs)*128 + row -> bank group = cl&7 (linear, conflict-free).
__global__ __launch_bounds__(512, 2) void gemm256p32(
    const f16* __restrict__ Ah, const f16* __restrict__ Al,
    const f16* __restrict__ Bh, const f16* __restrict__ Bl,
    const float* __restrict__ bias,
    f16* __restrict__ Chi, f16* __restrict__ Clo,
    int M, int N, int K) {
  extern __shared__ f16 lds[];
  constexpr int BS = 4 * 8192;

  const int tid  = threadIdx.x;
  const int wave = tid >> 6;
  const int lane = tid & 63;
  const int cl   = lane & 31;
  const int hs   = lane >> 5;

  const int nb  = N >> 8;
  const int nwg = (int)gridDim.x;
  const int qq  = nwg >> 3;
  const int sw  = ((int)blockIdx.x & 7) * qq + ((int)blockIdx.x >> 3);
  const int by  = sw / nb, bx = sw % nb;
  const int m0  = by << 8, n0 = bx << 8;

  const int wm = (wave >> 2) * 128;
  const int wn = (wave & 3) * 64;

  fx16 acc[4][2];
#pragma unroll
  for (int f = 0; f < 4; ++f)
#pragma unroll
    for (int g = 0; g < 2; ++g)
#pragma unroll
      for (int r = 0; r < 16; ++r) acc[f][g][r] = 0.f;

  // granule-major source: wave w, lane l -> row (w&1)*64+l, k-granule w>>1
  const int s_row = (wave & 1) * 64 + lane;
  const int s_g   = wave >> 1;
  // issue order: 0:Ah0 1:Ah1 2:Bh0 3:Bh1 4:Bl0 5:Bl1 6:Al0 7:Al1
  const f16* gsrc[8];
  int gdst[8];
  {
    int nr = 0;
    auto AR = [&](const f16* P, int mn, int reg, int rb) {
      gsrc[nr] = P + (size_t)(mn + rb + s_row) * K + s_g * 8;
      gdst[nr] = reg * 8192 + rb * 32 + wave * 512;
      ++nr;
    };
    AR(Ah, m0, 0, 0); AR(Ah, m0, 0, 128);
    AR(Bh, n0, 2, 0); AR(Bh, n0, 2, 128);
    AR(Bl, n0, 3, 0); AR(Bl, n0, 3, 128);
    AR(Al, m0, 1, 0); AR(Al, m0, 1, 128);
  }

#pragma unroll
  for (int r = 0; r < 8; ++r) gld16(gsrc[r], lds + gdst[r]);
  waitvm<4>();
  barrier_();

  const int KT = K >> 5;
  // read offsets (f16 units): plane (2k+hs)*1024 + row*8 within 4096-f16 half
  const int k0o = hs * 1024;
  const int k1o = (2 + hs) * 1024;
  const int ahalf = (wm >> 7) * 4096;            // A half per wave-row
  const int bh0 = ((wn >> 7) * 4096) + ((wn & 127) + cl) * 8;          // g=0
  const int bh1 = (((wn + 32) >> 7) * 4096) + (((wn + 32) & 127) + cl) * 8;

  for (int t = 0; t < KT; ++t) {
    f16* const sb  = lds + (t & 1) * BS;
    f16* const nsb = lds + ((t + 1) & 1) * BS;
    const int ktn = (t + 1 < KT ? t + 1 : t) * 32;

    const f16* sAh = sb + ahalf;
    const f16* sAl = sb + 8192 + ahalf;
    const f16* sBh = sb + 16384;
    const f16* sBl = sb + 24576;

    h8 ah[4][2], bh[2][2];
    // ---- phase 0: AhBh; issue Ah0,Ah1,Bh0 ----------------------------------
#pragma unroll
    for (int f = 0; f < 4; ++f) {
      const int ro = (f * 32 + cl) * 8;
      ah[f][0] = *(const h8*)(sAh + k0o + ro);
      ah[f][1] = *(const h8*)(sAh + k1o + ro);
    }
    bh[0][0] = *(const h8*)(sBh + k0o + bh0);
    bh[0][1] = *(const h8*)(sBh + k1o + bh0);
    bh[1][0] = *(const h8*)(sBh + k0o + bh1);
    bh[1][1] = *(const h8*)(sBh + k1o + bh1);
    gld16(gsrc[0] + ktn, nsb + gdst[0]);
    gld16(gsrc[1] + ktn, nsb + gdst[1]);
    gld16(gsrc[2] + ktn, nsb + gdst[2]);
    barrier_();
    asm volatile("s_waitcnt lgkmcnt(0)" ::: "memory");
    __builtin_amdgcn_sched_barrier(0);
    __builtin_amdgcn_s_setprio(1);
#pragma unroll
    for (int f = 0; f < 4; ++f)
#pragma unroll
      for (int g = 0; g < 2; ++g) {
        MFMA32_(acc[f][g], ah[f][0], bh[g][0]);
        MFMA32_(acc[f][g], ah[f][1], bh[g][1]);
      }
    __builtin_amdgcn_s_setprio(0);
    waitvm<5>();
    barrier_();
    // ---- phase 1: AhBl; issue Bh1,Bl0,Bl1 ----------------------------------
    {
      h8 bl[2][2];
      bl[0][0] = *(const h8*)(sBl + k0o + bh0);
      bl[0][1] = *(const h8*)(sBl + k1o + bh0);
      bl[1][0] = *(const h8*)(sBl + k0o + bh1);
      bl[1][1] = *(const h8*)(sBl + k1o + bh1);
      gld16(gsrc[3] + ktn, nsb + gdst[3]);
      gld16(gsrc[4] + ktn, nsb + gdst[4]);
      gld16(gsrc[5] + ktn, nsb + gdst[5]);
      barrier_();
      asm volatile("s_waitcnt lgkmcnt(0)" ::: "memory");
      __builtin_amdgcn_sched_barrier(0);
      __builtin_amdgcn_s_setprio(1);
#pragma unroll
      for (int f = 0; f < 4; ++f)
#pragma unroll
        for (int g = 0; g < 2; ++g) {
          MFMA32_(acc[f][g], ah[f][0], bl[g][0]);
          MFMA32_(acc[f][g], ah[f][1], bl[g][1]);
        }
      __builtin_amdgcn_s_setprio(0);
      waitvm<6>();
      barrier_();
    }
    // ---- phase 2: AlBh; issue Al0,Al1 --------------------------------------
    {
      h8 al[4][2];
#pragma unroll
      for (int f = 0; f < 4; ++f) {
        const int ro = (f * 32 + cl) * 8;
        al[f][0] = *(const h8*)(sAl + k0o + ro);
        al[f][1] = *(const h8*)(sAl + k1o + ro);
      }
      gld16(gsrc[6] + ktn, nsb + gdst[6]);
      gld16(gsrc[7] + ktn, nsb + gdst[7]);
      barrier_();
      asm volatile("s_waitcnt lgkmcnt(0)" ::: "memory");
      __builtin_amdgcn_sched_barrier(0);
      __builtin_amdgcn_s_setprio(1);
#pragma unroll
      for (int f = 0; f < 4; ++f)
#pragma unroll
        for (int g = 0; g < 2; ++g) {
          MFMA32_(acc[f][g], al[f][0], bh[g][0]);
          MFMA32_(acc[f][g], al[f][1], bh[g][1]);
        }
      __builtin_amdgcn_s_setprio(0);
      waitvm<4>();
      barrier_();
    }
  }

  // ---- epilogue: 32x32 C/D layout: col=cl, row=(r&3)+8*(r>>2)+4*hs ---------
#pragma unroll
  for (int f = 0; f < 4; ++f) {
#pragma unroll
    for (int g = 0; g < 2; ++g) {
      const int col = n0 + wn + g * 32 + cl;
      const float bb = bias[col];
#pragma unroll
      for (int r = 0; r < 16; ++r) {
        const int row = m0 + wm + f * 32 + (r & 3) + 8 * (r >> 2) + 4 * hs;
        const float v = fmaxf(acc[f][g][r] + bb, 0.f);
        const f16 hh = (f16)v;
        Chi[(size_t)row * N + col] = hh;
        Clo[(size_t)row * N + col] = (f16)(v - (float)hh);
      }
    }
  }
}

// ======= 256x256 1-term 32x32x16 GEMM, triple-buffered PD=2 =================
// Same granule-major LDS layout as gemm256p32.
template <int RELU>
__global__ __launch_bounds__(512, 2) void g1t32(
    const f16* __restrict__ Ah, const f16* __restrict__ Bh,
    const float* __restrict__ bias, f16* __restrict__ Chi,
    int M, int N, int K) {
  extern __shared__ f16 lds[];
  constexpr int BS = 16384;  // 32 KB per buffer, 3 buffers

  const int tid  = threadIdx.x;
  const int wave = tid >> 6;
  const int lane = tid & 63;
  const int cl   = lane & 31;
  const int hs   = lane >> 5;

  const int nb  = N >> 8;
  const int nwg = (int)gridDim.x;
  const int qq  = nwg >> 3;
  const int sw  = ((int)blockIdx.x & 7) * qq + ((int)blockIdx.x >> 3);
  const int by  = sw / nb, bx = sw % nb;
  const int m0  = by << 8, n0 = bx << 8;

  const int wm = (wave >> 2) * 128;
  const int wn = (wave & 3) * 64;

  fx16 acc[4][2];
#pragma unroll
  for (int f = 0; f < 4; ++f)
#pragma unroll
    for (int g = 0; g < 2; ++g)
#pragma unroll
      for (int r = 0; r < 16; ++r) acc[f][g][r] = 0.f;

  const int s_row = (wave & 1) * 64 + lane;
  const int s_g   = wave >> 1;
  const f16* gsrc[4];
  int gdst[4];
  {
    int nr = 0;
    auto AR = [&](const f16* P, int mn, int reg, int rb) {
      gsrc[nr] = P + (size_t)(mn + rb + s_row) * K + s_g * 8;
      gdst[nr] = reg * 8192 + rb * 32 + wave * 512;
      ++nr;
    };
    AR(Ah, m0, 0, 0); AR(Ah, m0, 0, 128);
    AR(Bh, n0, 1, 0); AR(Bh, n0, 1, 128);
  }

  const int KT  = K >> 5;
  const int k0o = hs * 1024;
  const int k1o = (2 + hs) * 1024;
  const int ahalf = (wm >> 7) * 4096;
  const int bh0 = ((wn >> 7) * 4096) + ((wn & 127) + cl) * 8;
  const int bh1 = (((wn + 32) >> 7) * 4096) + (((wn + 32) & 127) + cl) * 8;

#pragma unroll
  for (int r = 0; r < 4; ++r) gld16(gsrc[r], lds + gdst[r]);
#pragma unroll
  for (int r = 0; r < 4; ++r) gld16(gsrc[r] + 32, lds + BS + gdst[r]);

  int cur = 0, nn = 2;
  for (int t = 0; t < KT; ++t) {
    const int ktn = (t + 2 < KT ? t + 2 : KT - 1) * 32;
    f16* const nsb = lds + nn * BS;
#pragma unroll
    for (int r = 0; r < 4; ++r) gld16(gsrc[r] + ktn, nsb + gdst[r]);
    waitvm<8>();
    barrier_();

    const f16* sb = lds + cur * BS;
    const f16* sA = sb + ahalf;
    const f16* sB = sb + 8192;
    h8 a[4][2], b[2][2];
#pragma unroll
    for (int f = 0; f < 4; ++f) {
      const int ro = (f * 32 + cl) * 8;
      a[f][0] = *(const h8*)(sA + k0o + ro);
      a[f][1] = *(const h8*)(sA + k1o + ro);
    }
    b[0][0] = *(const h8*)(sB + k0o + bh0);
    b[0][1] = *(const h8*)(sB + k1o + bh0);
    b[1][0] = *(const h8*)(sB + k0o + bh1);
    b[1][1] = *(const h8*)(sB + k1o + bh1);
    asm volatile("s_waitcnt lgkmcnt(0)" ::: "memory");
    __builtin_amdgcn_sched_barrier(0);
    __builtin_amdgcn_s_setprio(1);
#pragma unroll
    for (int f = 0; f < 4; ++f)
#pragma unroll
      for (int g = 0; g < 2; ++g) {
        MFMA32_(acc[f][g], a[f][0], b[g][0]);
        MFMA32_(acc[f][g], a[f][1], b[g][1]);
      }
    __builtin_amdgcn_s_setprio(0);
    barrier_();
    cur = (cur == 2) ? 0 : cur + 1;
    nn  = (nn == 2) ? 0 : nn + 1;
  }

#pragma unroll
  for (int f = 0; f < 4; ++f) {
#pragma unroll
    for (int g = 0; g < 2; ++g) {
      const int col = n0 + wn + g * 32 + cl;
      const float bb = bias ? bias[col] : 0.f;
#pragma unroll
      for (int r = 0; r < 16; ++r) {
        const int row = m0 + wm + f * 32 + (r & 3) + 8 * (r >> 2) + 4 * hs;
        float v = acc[f][g][r] + bb;
        if constexpr (RELU) v = fmaxf(v, 0.f);
        Chi[(size_t)row * N + col] = (f16)v;
      }
    }
  }
}

// ====== weight transpose+convert: (K,N) fp32 -> (Npad,K) f16 hi[/lo] =======
template <int SPLIT>
__global__ __launch_bounds__(256) void wtransT(
    const float* __restrict__ src, f16* __restrict__ hi, f16* __restrict__ lo,
    int K, int N, int Npad) {
  __shared__ float t[32][33];
  const int bn = blockIdx.x * 32;
  const int bk = blockIdx.y * 32;
  const int tx = threadIdx.x & 31, ty = threadIdx.x >> 5;
#pragma unroll
  for (int r = ty; r < 32; r += 8) {
    const float v = (bn + tx < N) ? src[(size_t)(bk + r) * N + bn + tx] : 0.f;
    t[tx][r] = v;
  }
  __syncthreads();
#pragma unroll
  for (int r = ty; r < 32; r += 8) {
    const float v = t[r][tx];
    const f16 hh = (f16)v;
    hi[(size_t)(bn + r) * K + bk + tx] = hh;
    if (SPLIT) lo[(size_t)(bn + r) * K + bk + tx] = (f16)(v - (float)hh);
  }
}

// ====== reduce partials + bias -> logits; fused JAX categorical sample =====
__global__ __launch_bounds__(256) void reduce_sample(
    const float* __restrict__ part, const float* __restrict__ bias,
    float* __restrict__ logits_out, int* __restrict__ s_out,
    float* __restrict__ centers_out, uint32_t ka, uint32_t kb, int which) {
  const int tid = threadIdx.x;
  const int c = tid & 15;
  const int m = blockIdx.x * 16 + (tid >> 4);
  float v = bias[c];
#pragma unroll 8
  for (int s = 0; s < 32; ++s) v += part[((size_t)s * NT_ + m) * 16 + c];
  logits_out[(size_t)m * C_ + c] = v;
  const uint32_t j = (uint32_t)(m * C_ + c);
  uint32_t o0, o1;
  tf2x32(ka, kb, 0u, j, o0, o1);
  const uint32_t bits = o0 ^ o1;
  float u = __uint_as_float((bits >> 9) | 0x3f800000u) - 1.0f;
  u = fmaxf(1.17549435e-38f, u);
  float z = -logf(-logf(u)) + v;
  int bi = c;
#pragma unroll
  for (int st = 1; st < 16; st <<= 1) {
    const float oz = __shfl_xor(z, st);
    const int   ob = __shfl_xor(bi, st);
    if (oz > z || (oz == z && ob < bi)) { z = oz; bi = ob; }
  }
  if (c == 0) {
    s_out[m] = bi;
    centers_out[(size_t)m * G_ + which] = (float)bi;
  }
}

// ---------------- dec_in gather: codebook rows -> f16 ----------------------
__global__ void gather_dec_kernel(const float* __restrict__ codebook,
                                  const int* __restrict__ s1,
                                  const int* __restrict__ s2,
                                  f16* __restrict__ dec_in) {
  const int idx = blockIdx.x * blockDim.x + threadIdx.x;
  const int m = idx >> 9, d = idx & 511;
  const int g = d >> 8, dd = d & 255;
  const int s = g ? s2[m] : s1[m];
  dec_in[idx] = (f16)codebook[(size_t)(g * C_ + s) * D_ + dd];
}

// ------- final: decoded = dec_h@wd2+bd2 ; pred = decoded + P gather --------
__global__ __launch_bounds__(320) void final2(
    const f16* __restrict__ P,
    const float* __restrict__ bo3,
    const f16* __restrict__ dech,
    const float* __restrict__ wd2, const float* __restrict__ bd2,
    const int* __restrict__ s1, const int* __restrict__ s2,
    float* __restrict__ out_pred, float* __restrict__ out_dec) {
  __shared__ float drow[DECH_];
  const int m = blockIdx.x;
  for (int i = threadIdx.x; i < DECH_; i += 320)
    drow[i] = (float)dech[(size_t)m * DECH_ + i];
  __syncthreads();
  const int a1 = s1[m], a2 = s2[m];
  const int c = threadIdx.x >> 3, g = threadIdx.x & 7;
  float pdec = 0.f;
  if (c < WA_) {
    for (int i = 0; i < DECH_ / 8; ++i) {
      const int k = g * (DECH_ / 8) + i;
      pdec = fmaf(drow[k], wd2[(size_t)k * WA_ + c], pdec);
    }
  }
#pragma unroll
  for (int off = 1; off < 8; off <<= 1) pdec += __shfl_xor(pdec, off);
  if (c < WA_ && g == 0) {
    const float dec = pdec + bd2[c];
    const float soff = (float)P[(size_t)m * NPAD_ + a1 * WA_ + c]
                     + (float)P[(size_t)m * NPAD_ + C_ * WA_ + a2 * WA_ + c]
                     + bo3[a1 * WA_ + c] + bo3[C_ * WA_ + a2 * WA_ + c];
    out_dec[(size_t)m * WA_ + c] = dec;
    out_pred[(size_t)m * WA_ + c] = dec + soff;
  }
}

// ---------------------------------------------------------------------------
extern "C" void kernel_launch(void* const* d_in, const int* in_sizes, int n_in,
                              void* d_out, int out_size, void* d_ws, size_t ws_size,
                              hipStream_t stream) {
  const float* x    = (const float*)d_in[0];
  const float* w11  = (const float*)d_in[1];
  const float* b11  = (const float*)d_in[2];
  const float* w12  = (const float*)d_in[3];
  const float* b12  = (const float*)d_in[4];
  const float* w13  = (const float*)d_in[5];
  const float* b13  = (const float*)d_in[6];
  const float* w21  = (const float*)d_in[7];
  const float* b21  = (const float*)d_in[8];
  const float* w22  = (const float*)d_in[9];
  const float* b22  = (const float*)d_in[10];
  const float* wo1  = (const float*)d_in[11];
  const float* bo1  = (const float*)d_in[12];
  const float* wo2  = (const float*)d_in[13];
  const float* bo2  = (const float*)d_in[14];
  const float* wo3  = (const float*)d_in[15];
  const float* bo3  = (const float*)d_in[16];
  const float* cbk  = (const float*)d_in[17];
  const float* wd1  = (const float*)d_in[18];
  const float* bd1  = (const float*)d_in[19];
  const float* wd2  = (const float*)d_in[20];
  const float* bd2  = (const float*)d_in[21];

  float* out = (float*)d_out;
  float* out_pred = out;
  float* out_dec  = out + (size_t)NT_ * WA_;
  float* out_l1   = out + (size_t)2 * NT_ * WA_;
  float* out_l2   = out_l1 + (size_t)NT_ * C_;
  float* out_sc   = out_l2 + (size_t)NT_ * C_;

  const size_t AB = (size_t)NT_ * H_;
  f16*   Xh   = (f16*)d_ws;
  f16*   Xl   = Xh + AB;
  f16*   H1a  = Xl + AB;
  f16*   H1b  = H1a + AB;
  f16*   WH   = H1b + AB;
  f16*   WL   = WH + (size_t)H_ * H_;
  float* PART = (float*)(WL + (size_t)H_ * H_);
  int*   S1   = (int*)(PART + (size_t)32 * NT_ * C_);
  int*   S2   = S1 + NT_;

  f16* O1    = H1a;
  f16* O2    = H1b;
  f16* P     = Xh;                          // (NT, 1280) f16 = 20 MB <= 32
  f16* DECIN = Xl;
  f16* DECH  = Xl + (size_t)NT_ * DECH_;

  hipFuncSetAttribute(reinterpret_cast<const void*>(&gemm256p32),
                      hipFuncAttributeMaxDynamicSharedMemorySize, 131072);
  hipFuncSetAttribute(reinterpret_cast<const void*>(&gemm256<0,EPI_LOGIT>),
                      hipFuncAttributeMaxDynamicSharedMemorySize, 131072);
  hipFuncSetAttribute(reinterpret_cast<const void*>(&gemm256<1,EPI_LOGIT>),
                      hipFuncAttributeMaxDynamicSharedMemorySize, 131072);
  hipFuncSetAttribute(reinterpret_cast<const void*>(&g1t32<0>),
                      hipFuncAttributeMaxDynamicSharedMemorySize, 98304);
  hipFuncSetAttribute(reinterpret_cast<const void*>(&g1t32<1>),
                      hipFuncAttributeMaxDynamicSharedMemorySize, 98304);

  uint32_t k1a, k1b, k2a, k2b;
  tf2x32(0u, 42u, 0u, 0u, k1a, k1b);
  tf2x32(0u, 42u, 0u, 1u, k2a, k2b);

  const dim3 b256(256), b512(512);
  const dim3 gW(H_ / 32, H_ / 32);
  const dim3 gWo3(NPAD_ / 32, H_ / 32);           // (40,64)
  const dim3 gWd1(DECH_ / 32, DECH_ / 32);
  const dim3 gBig((NT_ / 256) * (H_ / 256));      // 256
  const dim3 gP((NT_ / 256) * (NPAD_ / 256));     // 160
  const dim3 gD((NT_ / 256) * (DECH_ / 256));     // 64

  // ---- x -> hi/lo split
  xsplit_kernel<<<NT_ * H_ / (8 * 256), b256, 0, stream>>>(x, Xh, Xl);

  // ---- bin1: h1 = relu(x@w11+b11)  [32x32 pair kernel]
  wtransT<1><<<gW, b256, 0, stream>>>(w11, WH, WL, H_, H_, H_);
  gemm256p32<<<gBig, b512, 131072, stream>>>(
      Xh, Xl, WH, WL, b11, H1a, H1b, NT_, H_, DIN_);
  // logits1 = relu(h1@w12+b12)@w13+b13 -> sample s1
  wtransT<1><<<gW, b256, 0, stream>>>(w12, WH, WL, H_, H_, H_);
  gemm256<0,EPI_LOGIT><<<gBig, b512, 131072, stream>>>(
      H1a, H1b, WH, WL, b12, nullptr, nullptr, NT_, H_, H_,
      nullptr, nullptr, 0, w13, PART);
  reduce_sample<<<NT_ / 16, b256, 0, stream>>>(PART, b13, out_l1, S1, out_sc,
                                               k1a, k1b, 0);

  // ---- bin2: logits2 = relu(x@w21[:2048] + w21[2048+s1] + b21)@w22+b22
  wtransT<1><<<gW, b256, 0, stream>>>(w21, WH, WL, H_, H_, H_);
  gemm256<1,EPI_LOGIT><<<gBig, b512, 131072, stream>>>(
      Xh, Xl, WH, WL, b21, nullptr, nullptr, NT_, H_, DIN_,
      S1, w21 + (size_t)DIN_ * H_, H_, w22, PART);
  reduce_sample<<<NT_ / 16, b256, 0, stream>>>(PART, b22, out_l2, S2, out_sc,
                                               k2a, k2b, 1);

  // ---- offsets: o1 = relu(x@wo1+bo1); o2 = relu(o1@wo2+bo2); P = o2@wo3
  wtransT<0><<<gW, b256, 0, stream>>>(wo1, WH, nullptr, H_, H_, H_);
  g1t32<1><<<gBig, b512, 98304, stream>>>(Xh, WH, bo1, O1, NT_, H_, DIN_);
  wtransT<0><<<gW, b256, 0, stream>>>(wo2, WH, nullptr, H_, H_, H_);
  g1t32<1><<<gBig, b512, 98304, stream>>>(O1, WH, bo2, O2, NT_, H_, H_);
  wtransT<0><<<gWo3, b256, 0, stream>>>(wo3, WH, nullptr, H_, G_ * C_ * WA_, NPAD_);
  g1t32<0><<<gP, b512, 98304, stream>>>(O2, WH, nullptr, P, NT_, NPAD_, H_);

  // ---- decoder: dec_h = relu(dec_in@wd1+bd1)
  gather_dec_kernel<<<(NT_ * DECH_) / 256, b256, 0, stream>>>(cbk, S1, S2, DECIN);
  wtransT<0><<<gWd1, b256, 0, stream>>>(wd1, WH, nullptr, DECH_, DECH_, DECH_);
  g1t32<1><<<gD, b512, 98304, stream>>>(DECIN, WH, bd1, DECH, NT_, DECH_, DECH_);

  // ---- final combine
  final2<<<NT_, 320, 0, stream>>>(P, bo3, DECH, wd2, bd2, S1, S2,
                                  out_pred, out_dec);

  (void)in_sizes; (void)n_in; (void)out_size; (void)ws_size;
}

// Round 8
// 967.041 us; speedup vs baseline: 1.1119x; 1.1119x over previous
//
#include <hip/hip_runtime.h>
#include <cstdint>
#include <cstddef>

// Problem dims (fixed by reference)
#define NT_   8192
#define DIN_  2048
#define H_    2048
#define C_    16
#define G_    2
#define D_    256
#define WA_   35
#define DECH_ 512
#define NPAD_ 1280   // 1120 padded to 5*256

typedef _Float16 f16;
typedef _Float16 h4 __attribute__((ext_vector_type(4)));
typedef _Float16 h8 __attribute__((ext_vector_type(8)));
typedef float fx4 __attribute__((ext_vector_type(4)));

typedef __attribute__((address_space(1))) const void gvoid_t;
typedef __attribute__((address_space(3))) void lvoid_t;

// async global->LDS, 16B per lane; LDS dest = wave-uniform base + lane*16
__device__ __forceinline__ void gld16(const void* g, void* l) {
  __builtin_amdgcn_global_load_lds((gvoid_t*)(uintptr_t)g,
                                   (lvoid_t*)(uint32_t)(uintptr_t)l, 16, 0, 0);
}

__device__ __forceinline__ void barrier_() {
  asm volatile("" ::: "memory");
  __builtin_amdgcn_s_barrier();
  asm volatile("" ::: "memory");
}

template <int N>
__device__ __forceinline__ void waitvm() {
  if constexpr (N == 8)      asm volatile("s_waitcnt vmcnt(8)" ::: "memory");
  else if constexpr (N == 6) asm volatile("s_waitcnt vmcnt(6)" ::: "memory");
  else if constexpr (N == 2) asm volatile("s_waitcnt vmcnt(2)" ::: "memory");
  else                       asm volatile("s_waitcnt vmcnt(0)" ::: "memory");
}

#define MFMA_(d, a, b) d = __builtin_amdgcn_mfma_f32_16x16x32_f16(a, b, d, 0, 0, 0)

// ---------------- threefry2x32 (Random123 / JAX-compatible) ----------------
__host__ __device__ inline void tf2x32(uint32_t k0, uint32_t k1,
                                       uint32_t x0, uint32_t x1,
                                       uint32_t& o0, uint32_t& o1) {
  const uint32_t ks2 = k0 ^ k1 ^ 0x1BD11BDAu;
  uint32_t ks[3] = {k0, k1, ks2};
  x0 += ks[0]; x1 += ks[1];
  const uint32_t R0[4] = {13u, 15u, 26u, 6u};
  const uint32_t R1[4] = {17u, 29u, 16u, 24u};
#pragma unroll
  for (int g = 0; g < 5; ++g) {
    const uint32_t* R = (g & 1) ? R1 : R0;
#pragma unroll
    for (int r = 0; r < 4; ++r) {
      x0 += x1;
      x1 = (x1 << R[r]) | (x1 >> (32u - R[r]));
      x1 ^= x0;
    }
    x0 += ks[(g + 1) % 3];
    x1 += ks[(g + 2) % 3] + (uint32_t)(g + 1);
  }
  o0 = x0; o1 = x1;
}

// ---------------- x split: fp32 -> f16 hi/lo --------------------------------
__global__ __launch_bounds__(256) void xsplit_kernel(
    const float* __restrict__ x, f16* __restrict__ xh, f16* __restrict__ xl) {
  const size_t i = (size_t)blockIdx.x * 256 + threadIdx.x;  // per 8 floats
  const float4 v0 = *(const float4*)(x + i * 8);
  const float4 v1 = *(const float4*)(x + i * 8 + 4);
  float vv[8] = {v0.x, v0.y, v0.z, v0.w, v1.x, v1.y, v1.z, v1.w};
  h8 hh, ll;
#pragma unroll
  for (int k = 0; k < 8; ++k) {
    const f16 h = (f16)vv[k];
    hh[k] = h;
    ll[k] = (f16)(vv[k] - (float)h);
  }
  *(h8*)(xh + i * 8) = hh;
  *(h8*)(xl + i * 8) = ll;
}

// ============ 256x256 3-term 16x16x32 GEMM, 2 barriers/K-tile ===============
// A=(M,K) f16 hi/lo; B=(N,K) f16 hi/lo. Terms: AhBh + AhBl + AlBh.
// Only correctness fences kept: waitvm<6>+barrier (Al staging fence) and
// waitvm<2>+barrier (tile-end buffer swap). ds_read<->MFMA overlap is left
// to the compiler's fine-grained lgkmcnt scheduling (no lgkm(0) pins).
enum { EPI_PAIR = 0, EPI_HI = 1, EPI_LOGIT = 2 };

template <int GATHER, int EPI>
__global__ __launch_bounds__(512, 2) void gemm256(
    const f16* __restrict__ Ah, const f16* __restrict__ Al,
    const f16* __restrict__ Bh, const f16* __restrict__ Bl,
    const float* __restrict__ bias,
    f16* __restrict__ Chi, f16* __restrict__ Clo,
    int M, int N, int K,
    const int* __restrict__ gidx, const float* __restrict__ growp, int gldw,
    const float* __restrict__ wlog, float* __restrict__ part) {
  extern __shared__ f16 lds[];
  constexpr int BS = 4 * 8192;

  const int tid  = threadIdx.x;
  const int wave = tid >> 6;
  const int lane = tid & 63;
  const int lr   = lane & 15;

  // bijective XCD swizzle (nwg % 8 == 0)
  const int nb  = N >> 8;
  const int nwg = (int)gridDim.x;
  const int qq  = nwg >> 3;
  const int sw  = ((int)blockIdx.x & 7) * qq + ((int)blockIdx.x >> 3);
  const int by  = sw / nb, bx = sw % nb;
  const int m0  = by << 8, n0 = bx << 8;

  const int wm = (wave >> 2) * 128;
  const int wn = (wave & 3) * 64;

  fx4 acc[8][4];
#pragma unroll
  for (int i = 0; i < 8; ++i)
#pragma unroll
    for (int j = 0; j < 4; ++j) acc[i][j] = (fx4){0.f, 0.f, 0.f, 0.f};

  const int r_row = wave * 16 + (lane >> 2);
  const int r_g   = (lane & 3) ^ ((lane >> 3) & 3);  // src granule swizzle
  // issue order: 0:Bh0 1:Bh1 2:Bl0 3:Bl1 4:Ah0 5:Ah1 6:Al0 7:Al1
  const f16* gsrc[8];
  int gdst[8];
  {
    int nr = 0;
    auto AR = [&](const f16* P, int mn, int reg, int rb) {
      gsrc[nr] = P + (size_t)(mn + rb + r_row) * K + r_g * 8;
      gdst[nr] = reg * 8192 + rb * 32 + wave * 512;
      ++nr;
    };
    AR(Bh, n0, 2, 0); AR(Bh, n0, 2, 128);
    AR(Bl, n0, 3, 0); AR(Bl, n0, 3, 128);
    AR(Ah, m0, 0, 0); AR(Ah, m0, 0, 128);
    AR(Al, m0, 1, 0); AR(Al, m0, 1, 128);
  }

  // prologue: stage tile 0; B+Ah must land, Al may stay in flight
#pragma unroll
  for (int r = 0; r < 8; ++r) gld16(gsrc[r], lds + gdst[r]);
  waitvm<2>();
  barrier_();

  const int pg8 = ((lane >> 4) ^ ((lr >> 1) & 3)) * 8;  // read-side swizzle
  const int KT  = K >> 5;

  for (int t = 0; t < KT; ++t) {
    f16* const sb  = lds + (t & 1) * BS;
    f16* const nsb = lds + ((t + 1) & 1) * BS;
    const int ktn = (t + 1 < KT ? t + 1 : t) * 32;  // phantom tail reload

    const f16* sAh = sb;
    const f16* sAl = sb + 8192;
    const f16* sBh = sb + 16384;
    const f16* sBl = sb + 24576;

    // ---- region 1: B(h,l) + Ah both halves; 64 MFMA; issue 6 stages ------
    h8 vbh[4], vbl[4], va[4], va2[4];
#pragma unroll
    for (int j = 0; j < 4; ++j) {
      vbh[j] = *(const h8*)(sBh + (wn + j * 16 + lr) * 32 + pg8);
      vbl[j] = *(const h8*)(sBl + (wn + j * 16 + lr) * 32 + pg8);
    }
#pragma unroll
    for (int i = 0; i < 4; ++i) {
      va[i]  = *(const h8*)(sAh + (wm + i * 16 + lr) * 32 + pg8);
      va2[i] = *(const h8*)(sAh + (wm + 64 + i * 16 + lr) * 32 + pg8);
    }
    gld16(gsrc[0] + ktn, nsb + gdst[0]);
    gld16(gsrc[1] + ktn, nsb + gdst[1]);
    gld16(gsrc[2] + ktn, nsb + gdst[2]);
    gld16(gsrc[3] + ktn, nsb + gdst[3]);
    gld16(gsrc[4] + ktn, nsb + gdst[4]);
    gld16(gsrc[5] + ktn, nsb + gdst[5]);
    __builtin_amdgcn_s_setprio(1);
#pragma unroll
    for (int i = 0; i < 4; ++i)
#pragma unroll
      for (int j = 0; j < 4; ++j) MFMA_(acc[i][j], va[i], vbh[j]);
#pragma unroll
    for (int i = 0; i < 4; ++i)
#pragma unroll
      for (int j = 0; j < 4; ++j) MFMA_(acc[i][j], va[i], vbl[j]);
#pragma unroll
    for (int i = 0; i < 4; ++i)
#pragma unroll
      for (int j = 0; j < 4; ++j) MFMA_(acc[4 + i][j], va2[i], vbh[j]);
#pragma unroll
    for (int i = 0; i < 4; ++i)
#pragma unroll
      for (int j = 0; j < 4; ++j) MFMA_(acc[4 + i][j], va2[i], vbl[j]);
    __builtin_amdgcn_s_setprio(0);
    // fence: this buffer's Al slices (2 oldest outstanding) landed block-wide
    waitvm<6>();
    barrier_();
    // ---- region 2: Al x Bh; 32 MFMA; issue 2 stages -----------------------
    {
      h8 vl0[4], vl1[4];
#pragma unroll
      for (int i = 0; i < 4; ++i) {
        vl0[i] = *(const h8*)(sAl + (wm + i * 16 + lr) * 32 + pg8);
        vl1[i] = *(const h8*)(sAl + (wm + 64 + i * 16 + lr) * 32 + pg8);
      }
      gld16(gsrc[6] + ktn, nsb + gdst[6]);
      gld16(gsrc[7] + ktn, nsb + gdst[7]);
      __builtin_amdgcn_s_setprio(1);
#pragma unroll
      for (int i = 0; i < 4; ++i)
#pragma unroll
        for (int j = 0; j < 4; ++j) {
          MFMA_(acc[i][j], vl0[i], vbh[j]);
          MFMA_(acc[4 + i][j], vl1[i], vbh[j]);
        }
      __builtin_amdgcn_s_setprio(0);
      // fence: next buffer's B+Ah (6 oldest of this tile's 8) landed
      waitvm<2>();
      barrier_();
    }
  }

  // ---- epilogues ----
  const int rq = (lane >> 4) * 4;
  if constexpr (EPI == EPI_LOGIT) {
    // finalize h-tile in regs: bias [+gather] + relu
#pragma unroll
    for (int mi = 0; mi < 8; ++mi) {
#pragma unroll
      for (int q = 0; q < 4; ++q) {
        const int row = m0 + wm + mi * 16 + rq + q;
        const float* gr = nullptr;
        if constexpr (GATHER) gr = growp + (size_t)gidx[row] * gldw;
#pragma unroll
        for (int j = 0; j < 4; ++j) {
          const int col = n0 + wn + j * 16 + lr;
          float v = acc[mi][j][q] + bias[col];
          if constexpr (GATHER) v += gr[col];
          acc[mi][j][q] = fmaxf(v, 0.f);
        }
      }
    }
    // drain phantom staging, then reuse LDS for coalesced PART writes
    waitvm<0>();
    barrier_();
    float* psm = (float*)lds + wave * 2560;  // 8mi x 16rows x stride20
    const int sidx = bx * 4 + (wave & 3);
    const int q_l = ((lr & 1) << 1) | ((lr >> 1) & 1);   // bitrev mapping
    const int c_l = (((lr >> 2) & 1) << 1) | ((lr >> 3) & 1);
#pragma unroll
    for (int cc = 0; cc < 4; ++cc) {
      float wc[4][4];
#pragma unroll
      for (int j = 0; j < 4; ++j) {
        const float4 wv = *(const float4*)(wlog +
            (size_t)(n0 + wn + j * 16 + lr) * 16 + cc * 4);
        wc[j][0] = wv.x; wc[j][1] = wv.y; wc[j][2] = wv.z; wc[j][3] = wv.w;
      }
#pragma unroll
      for (int mi = 0; mi < 8; ++mi) {
        float A[16];
#pragma unroll
        for (int i = 0; i < 16; ++i) {
          float s = 0.f;
#pragma unroll
          for (int j = 0; j < 4; ++j)
            s = fmaf(acc[mi][j][i >> 2], wc[j][i & 3], s);
          A[i] = s;
        }
        // distribute-reduce over the 16-lane group: lane lr ends with its
        // (q_l,c_l) total; all indices compile-time (no scratch).
#pragma unroll
        for (int k = 0; k < 4; ++k) {
          const int L2 = 8 >> k;
          const bool b = (lr >> k) & 1;
          float An[8];
#pragma unroll
          for (int i = 0; i < L2; ++i) {
            const float keep = b ? A[i + L2] : A[i];
            const float send = b ? A[i] : A[i + L2];
            An[i] = keep + __shfl_xor(send, 1 << k);
          }
#pragma unroll
          for (int i = 0; i < L2; ++i) A[i] = An[i];
        }
        psm[mi * 320 + (rq + q_l) * 20 + cc * 4 + c_l] = A[0];
      }
    }
    asm volatile("s_waitcnt lgkmcnt(0)" ::: "memory");
#pragma unroll
    for (int mi = 0; mi < 8; ++mi) {
      const float4 o = *(const float4*)(psm + mi * 320 +
                                        (lane >> 2) * 20 + (lane & 3) * 4);
      float* pout = part + ((size_t)sidx * NT_ +
                            (m0 + wm + mi * 16 + (lane >> 2))) * 16 +
                    (lane & 3) * 4;
      *(float4*)pout = o;
    }
  } else {
#pragma unroll
    for (int mi = 0; mi < 8; ++mi) {
#pragma unroll
      for (int q = 0; q < 4; ++q) {
        const int row = m0 + wm + mi * 16 + rq + q;
#pragma unroll
        for (int j = 0; j < 4; ++j) {
          const int col = n0 + wn + j * 16 + lr;
          float v = fmaxf(acc[mi][j][q] + bias[col], 0.f);
          const f16 hh = (f16)v;
          Chi[(size_t)row * N + col] = hh;
          if constexpr (EPI == EPI_PAIR)
            Clo[(size_t)row * N + col] = (f16)(v - (float)hh);
        }
      }
    }
  }
}

// ============ 256x256-tile 1-term 16x16x32 GEMM, triple-buffered PD=2 =======
template <int RELU>
__global__ __launch_bounds__(512, 2) void gemm256_1t(
    const f16* __restrict__ Ah, const f16* __restrict__ Bh,
    const float* __restrict__ bias, f16* __restrict__ Chi,
    int M, int N, int K) {
  extern __shared__ f16 lds[];
  constexpr int BS = 16384;  // 32 KB per buffer, 3 buffers

  const int tid  = threadIdx.x;
  const int wave = tid >> 6;
  const int lane = tid & 63;
  const int lr   = lane & 15;

  const int nb  = N >> 8;
  const int nwg = (int)gridDim.x;
  const int qq  = nwg >> 3;
  const int sw  = ((int)blockIdx.x & 7) * qq + ((int)blockIdx.x >> 3);
  const int by  = sw / nb, bx = sw % nb;
  const int m0  = by << 8, n0 = bx << 8;

  const int wm = (wave >> 2) * 128;
  const int wn = (wave & 3) * 64;

  fx4 acc[8][4];
#pragma unroll
  for (int i = 0; i < 8; ++i)
#pragma unroll
    for (int j = 0; j < 4; ++j) acc[i][j] = (fx4){0.f, 0.f, 0.f, 0.f};

  const int r_row = wave * 16 + (lane >> 2);
  const int r_g   = (lane & 3) ^ ((lane >> 3) & 3);
  // regions: 0:Ah0 1:Ah1 2:Bh0 3:Bh1 (A at f16 0, B at 8192)
  const f16* gsrc[4];
  int gdst[4];
  {
    int nr = 0;
    auto AR = [&](const f16* P, int mn, int reg, int rb) {
      gsrc[nr] = P + (size_t)(mn + rb + r_row) * K + r_g * 8;
      gdst[nr] = reg * 8192 + rb * 32 + wave * 512;
      ++nr;
    };
    AR(Ah, m0, 0, 0); AR(Ah, m0, 0, 128);
    AR(Bh, n0, 1, 0); AR(Bh, n0, 1, 128);
  }

  const int KT  = K >> 5;
  const int pg8 = ((lane >> 4) ^ ((lr >> 1) & 3)) * 8;

  // prologue: tiles 0 and 1
#pragma unroll
  for (int r = 0; r < 4; ++r) gld16(gsrc[r], lds + gdst[r]);
#pragma unroll
  for (int r = 0; r < 4; ++r) gld16(gsrc[r] + 32, lds + BS + gdst[r]);

  int cur = 0, nn = 2;
  for (int t = 0; t < KT; ++t) {
    const int ktn = (t + 2 < KT ? t + 2 : KT - 1) * 32;
    f16* const nsb = lds + nn * BS;
#pragma unroll
    for (int r = 0; r < 4; ++r) gld16(gsrc[r] + ktn, nsb + gdst[r]);
    waitvm<8>();  // tile t's 4 loads landed; t+1/t+2's 8 stay in flight
    barrier_();

    const f16* sb = lds + cur * BS;
    h8 vb[4], va0[4], va1[4];
#pragma unroll
    for (int j = 0; j < 4; ++j)
      vb[j] = *(const h8*)(sb + 8192 + (wn + j * 16 + lr) * 32 + pg8);
#pragma unroll
    for (int i = 0; i < 4; ++i) {
      va0[i] = *(const h8*)(sb + (wm + i * 16 + lr) * 32 + pg8);
      va1[i] = *(const h8*)(sb + (wm + 64 + i * 16 + lr) * 32 + pg8);
    }
    __builtin_amdgcn_s_setprio(1);
#pragma unroll
    for (int i = 0; i < 4; ++i)
#pragma unroll
      for (int j = 0; j < 4; ++j) {
        MFMA_(acc[i][j], va0[i], vb[j]);
        MFMA_(acc[4 + i][j], va1[i], vb[j]);
      }
    __builtin_amdgcn_s_setprio(0);
    barrier_();
    cur = (cur == 2) ? 0 : cur + 1;
    nn  = (nn == 2) ? 0 : nn + 1;
  }

  const int rq = (lane >> 4) * 4;
#pragma unroll
  for (int mi = 0; mi < 8; ++mi) {
#pragma unroll
    for (int q = 0; q < 4; ++q) {
      const int row = m0 + wm + mi * 16 + rq + q;
#pragma unroll
      for (int j = 0; j < 4; ++j) {
        const int col = n0 + wn + j * 16 + lr;
        float v = acc[mi][j][q];
        if (bias) v += bias[col];
        if constexpr (RELU) v = fmaxf(v, 0.f);
        Chi[(size_t)row * N + col] = (f16)v;
      }
    }
  }
}

// ====== weight transpose+convert: (K,N) fp32 -> (Npad,K) f16 hi[/lo] =======
template <int SPLIT>
__global__ __launch_bounds__(256) void wtransT(
    const float* __restrict__ src, f16* __restrict__ hi, f16* __restrict__ lo,
    int K, int N, int Npad) {
  __shared__ float t[32][33];
  const int bn = blockIdx.x * 32;
  const int bk = blockIdx.y * 32;
  const int tx = threadIdx.x & 31, ty = threadIdx.x >> 5;
#pragma unroll
  for (int r = ty; r < 32; r += 8) {
    const float v = (bn + tx < N) ? src[(size_t)(bk + r) * N + bn + tx] : 0.f;
    t[tx][r] = v;
  }
  __syncthreads();
#pragma unroll
  for (int r = ty; r < 32; r += 8) {
    const float v = t[r][tx];
    const f16 hh = (f16)v;
    hi[(size_t)(bn + r) * K + bk + tx] = hh;
    if (SPLIT) lo[(size_t)(bn + r) * K + bk + tx] = (f16)(v - (float)hh);
  }
}

// ====== reduce partials + bias -> logits; fused JAX categorical sample =====
__global__ __launch_bounds__(256) void reduce_sample(
    const float* __restrict__ part, const float* __restrict__ bias,
    float* __restrict__ logits_out, int* __restrict__ s_out,
    float* __restrict__ centers_out, uint32_t ka, uint32_t kb, int which) {
  const int tid = threadIdx.x;
  const int c = tid & 15;
  const int m = blockIdx.x * 16 + (tid >> 4);
  float v = bias[c];
#pragma unroll 8
  for (int s = 0; s < 32; ++s) v += part[((size_t)s * NT_ + m) * 16 + c];
  logits_out[(size_t)m * C_ + c] = v;
  // gumbel (JAX threefry bits, partitionable path)
  const uint32_t j = (uint32_t)(m * C_ + c);
  uint32_t o0, o1;
  tf2x32(ka, kb, 0u, j, o0, o1);
  const uint32_t bits = o0 ^ o1;
  float u = __uint_as_float((bits >> 9) | 0x3f800000u) - 1.0f;
  u = fmaxf(1.17549435e-38f, u);
  float z = -logf(-logf(u)) + v;
  int bi = c;
#pragma unroll
  for (int st = 1; st < 16; st <<= 1) {
    const float oz = __shfl_xor(z, st);
    const int   ob = __shfl_xor(bi, st);
    if (oz > z || (oz == z && ob < bi)) { z = oz; bi = ob; }
  }
  if (c == 0) {
    s_out[m] = bi;
    centers_out[(size_t)m * G_ + which] = (float)bi;
  }
}

// ---------------- dec_in gather: codebook rows -> f16 ----------------------
__global__ void gather_dec_kernel(const float* __restrict__ codebook,
                                  const int* __restrict__ s1,
                                  const int* __restrict__ s2,
                                  f16* __restrict__ dec_in) {
  const int idx = blockIdx.x * blockDim.x + threadIdx.x;
  const int m = idx >> 9, d = idx & 511;
  const int g = d >> 8, dd = d & 255;
  const int s = g ? s2[m] : s1[m];
  dec_in[idx] = (f16)codebook[(size_t)(g * C_ + s) * D_ + dd];
}

// ------- final: decoded = dec_h@wd2+bd2 ; pred = decoded + P gather --------
__global__ __launch_bounds__(320) void final2(
    const f16* __restrict__ P,
    const float* __restrict__ bo3,
    const f16* __restrict__ dech,
    const float* __restrict__ wd2, const float* __restrict__ bd2,
    const int* __restrict__ s1, const int* __restrict__ s2,
    float* __restrict__ out_pred, float* __restrict__ out_dec) {
  __shared__ float drow[DECH_];
  const int m = blockIdx.x;
  for (int i = threadIdx.x; i < DECH_; i += 320)
    drow[i] = (float)dech[(size_t)m * DECH_ + i];
  __syncthreads();
  const int a1 = s1[m], a2 = s2[m];
  const int c = threadIdx.x >> 3, g = threadIdx.x & 7;
  float pdec = 0.f;
  if (c < WA_) {
    for (int i = 0; i < DECH_ / 8; ++i) {
      const int k = g * (DECH_ / 8) + i;
      pdec = fmaf(drow[k], wd2[(size_t)k * WA_ + c], pdec);
    }
  }
#pragma unroll
  for (int off = 1; off < 8; off <<= 1) pdec += __shfl_xor(pdec, off);
  if (c < WA_ && g == 0) {
    const float dec = pdec + bd2[c];
    const float soff = (float)P[(size_t)m * NPAD_ + a1 * WA_ + c]
                     + (float)P[(size_t)m * NPAD_ + C_ * WA_ + a2 * WA_ + c]
                     + bo3[a1 * WA_ + c] + bo3[C_ * WA_ + a2 * WA_ + c];
    out_dec[(size_t)m * WA_ + c] = dec;
    out_pred[(size_t)m * WA_ + c] = dec + soff;
  }
}

// ---------------------------------------------------------------------------
extern "C" void kernel_launch(void* const* d_in, const int* in_sizes, int n_in,
                              void* d_out, int out_size, void* d_ws, size_t ws_size,
                              hipStream_t stream) {
  const float* x    = (const float*)d_in[0];
  const float* w11  = (const float*)d_in[1];
  const float* b11  = (const float*)d_in[2];
  const float* w12  = (const float*)d_in[3];
  const float* b12  = (const float*)d_in[4];
  const float* w13  = (const float*)d_in[5];
  const float* b13  = (const float*)d_in[6];
  const float* w21  = (const float*)d_in[7];
  const float* b21  = (const float*)d_in[8];
  const float* w22  = (const float*)d_in[9];
  const float* b22  = (const float*)d_in[10];
  const float* wo1  = (const float*)d_in[11];
  const float* bo1  = (const float*)d_in[12];
  const float* wo2  = (const float*)d_in[13];
  const float* bo2  = (const float*)d_in[14];
  const float* wo3  = (const float*)d_in[15];
  const float* bo3  = (const float*)d_in[16];
  const float* cbk  = (const float*)d_in[17];
  const float* wd1  = (const float*)d_in[18];
  const float* bd1  = (const float*)d_in[19];
  const float* wd2  = (const float*)d_in[20];
  const float* bd2  = (const float*)d_in[21];

  float* out = (float*)d_out;
  float* out_pred = out;
  float* out_dec  = out + (size_t)NT_ * WA_;
  float* out_l1   = out + (size_t)2 * NT_ * WA_;
  float* out_l2   = out_l1 + (size_t)NT_ * C_;
  float* out_sc   = out_l2 + (size_t)NT_ * C_;

  const size_t AB = (size_t)NT_ * H_;
  f16*   Xh   = (f16*)d_ws;
  f16*   Xl   = Xh + AB;
  f16*   H1a  = Xl + AB;
  f16*   H1b  = H1a + AB;
  f16*   WH   = H1b + AB;
  f16*   WL   = WH + (size_t)H_ * H_;
  float* PART = (float*)(WL + (size_t)H_ * H_);
  int*   S1   = (int*)(PART + (size_t)32 * NT_ * C_);
  int*   S2   = S1 + NT_;

  f16* O1    = H1a;
  f16* O2    = H1b;
  f16* P     = Xh;                          // (NT, 1280) f16 = 20 MB <= 32
  f16* DECIN = Xl;
  f16* DECH  = Xl + (size_t)NT_ * DECH_;

  hipFuncSetAttribute(reinterpret_cast<const void*>(&gemm256<0,EPI_PAIR>),
                      hipFuncAttributeMaxDynamicSharedMemorySize, 131072);
  hipFuncSetAttribute(reinterpret_cast<const void*>(&gemm256<0,EPI_LOGIT>),
                      hipFuncAttributeMaxDynamicSharedMemorySize, 131072);
  hipFuncSetAttribute(reinterpret_cast<const void*>(&gemm256<1,EPI_LOGIT>),
                      hipFuncAttributeMaxDynamicSharedMemorySize, 131072);
  hipFuncSetAttribute(reinterpret_cast<const void*>(&gemm256_1t<0>),
                      hipFuncAttributeMaxDynamicSharedMemorySize, 98304);
  hipFuncSetAttribute(reinterpret_cast<const void*>(&gemm256_1t<1>),
                      hipFuncAttributeMaxDynamicSharedMemorySize, 98304);

  // subkeys of jax.random.split(jax.random.key(42)); key data = [0,42]
  uint32_t k1a, k1b, k2a, k2b;
  tf2x32(0u, 42u, 0u, 0u, k1a, k1b);
  tf2x32(0u, 42u, 0u, 1u, k2a, k2b);

  const dim3 b256(256), b512(512);
  const dim3 gW(H_ / 32, H_ / 32);
  const dim3 gWo3(NPAD_ / 32, H_ / 32);           // (40,64)
  const dim3 gWd1(DECH_ / 32, DECH_ / 32);
  const dim3 gBig((NT_ / 256) * (H_ / 256));      // 256
  const dim3 gP((NT_ / 256) * (NPAD_ / 256));     // 160
  const dim3 gD((NT_ / 256) * (DECH_ / 256));     // 64

  // ---- x -> hi/lo split (feeds w11, w21, wo1)
  xsplit_kernel<<<NT_ * H_ / (8 * 256), b256, 0, stream>>>(x, Xh, Xl);

  // ---- bin1: h1 = relu(x@w11+b11); logits1 = relu(h1@w12+b12)@w13+b13
  wtransT<1><<<gW, b256, 0, stream>>>(w11, WH, WL, H_, H_, H_);
  gemm256<0,EPI_PAIR><<<gBig, b512, 131072, stream>>>(
      Xh, Xl, WH, WL, b11, H1a, H1b, NT_, H_, DIN_,
      nullptr, nullptr, 0, nullptr, nullptr);
  wtransT<1><<<gW, b256, 0, stream>>>(w12, WH, WL, H_, H_, H_);
  gemm256<0,EPI_LOGIT><<<gBig, b512, 131072, stream>>>(
      H1a, H1b, WH, WL, b12, nullptr, nullptr, NT_, H_, H_,
      nullptr, nullptr, 0, w13, PART);
  reduce_sample<<<NT_ / 16, b256, 0, stream>>>(PART, b13, out_l1, S1, out_sc,
                                               k1a, k1b, 0);

  // ---- bin2: logits2 = relu(x@w21[:2048] + w21[2048+s1] + b21)@w22+b22
  wtransT<1><<<gW, b256, 0, stream>>>(w21, WH, WL, H_, H_, H_);
  gemm256<1,EPI_LOGIT><<<gBig, b512, 131072, stream>>>(
      Xh, Xl, WH, WL, b21, nullptr, nullptr, NT_, H_, DIN_,
      S1, w21 + (size_t)DIN_ * H_, H_, w22, PART);
  reduce_sample<<<NT_ / 16, b256, 0, stream>>>(PART, b22, out_l2, S2, out_sc,
                                               k2a, k2b, 1);

  // ---- offsets: o1 = relu(x@wo1+bo1); o2 = relu(o1@wo2+bo2); P = o2@wo3
  wtransT<0><<<gW, b256, 0, stream>>>(wo1, WH, nullptr, H_, H_, H_);
  gemm256_1t<1><<<gBig, b512, 98304, stream>>>(Xh, WH, bo1, O1, NT_, H_, DIN_);
  wtransT<0><<<gW, b256, 0, stream>>>(wo2, WH, nullptr, H_, H_, H_);
  gemm256_1t<1><<<gBig, b512, 98304, stream>>>(O1, WH, bo2, O2, NT_, H_, H_);
  wtransT<0><<<gWo3, b256, 0, stream>>>(wo3, WH, nullptr, H_, G_ * C_ * WA_, NPAD_);
  gemm256_1t<0><<<gP, b512, 98304, stream>>>(O2, WH, nullptr, P, NT_, NPAD_, H_);

  // ---- decoder: dec_h = relu(dec_in@wd1+bd1)
  gather_dec_kernel<<<(NT_ * DECH_) / 256, b256, 0, stream>>>(cbk, S1, S2, DECIN);
  wtransT<0><<<gWd1, b256, 0, stream>>>(wd1, WH, nullptr, DECH_, DECH_, DECH_);
  gemm256_1t<1><<<gD, b512, 98304, stream>>>(DECIN, WH, bd1, DECH, NT_, DECH_, DECH_);

  // ---- final combine
  final2<<<NT_, 320, 0, stream>>>(P, bo3, DECH, wd2, bd2, S1, S2,
                                  out_pred, out_dec);

  (void)in_sizes; (void)n_in; (void)out_size; (void)ws_size;
}